// Round 11
// baseline (1176.795 us; speedup 1.0000x reference)
//
#include <hip/hip_runtime.h>
#include <hip/hip_bf16.h>

typedef __attribute__((ext_vector_type(8))) _Float16 half8_t;
typedef __attribute__((ext_vector_type(4))) _Float16 half4_t;
typedef __attribute__((ext_vector_type(4))) float float4_t;

#define D_DIM 768
#define S_DIM 4096
#define B_DIM 4
#define M_DIM (B_DIM * S_DIM)  // 16384
#define SD ((size_t)S_DIM * D_DIM)

#define GLOAD_LDS16(g, s)                                      \
  __builtin_amdgcn_global_load_lds(                            \
      (const __attribute__((address_space(1))) void*)(g),      \
      (__attribute__((address_space(3))) void*)(s), 16, 0, 0)

__device__ __forceinline__ float4_t mfma16(half8_t a, half8_t b, float4_t c) {
  return __builtin_amdgcn_mfma_f32_16x16x32_f16(a, b, c, 0, 0, 0);
}

// ---------------- x -> fp16 (vectorized) ----------------
__global__ __launch_bounds__(256) void cvt_x_kernel(const float* __restrict__ in,
                                                    _Float16* __restrict__ out, int n) {
  int i = (blockIdx.x * 256 + threadIdx.x) * 4;
  if (i < n) {
    float4 v = *(const float4*)(in + i);
    half4_t o;
    o.x = (_Float16)v.x; o.y = (_Float16)v.y; o.z = (_Float16)v.z; o.w = (_Float16)v.w;
    *(half4_t*)(out + i) = o;
  }
}

// ---------------- W (fp32 [k][n]) -> WT (fp16 [n][k]) ----------------
__global__ __launch_bounds__(256) void transpose_w_kernel(const float* __restrict__ W0,
                                                          const float* __restrict__ W1,
                                                          const float* __restrict__ W2,
                                                          _Float16* __restrict__ WT) {
  const float* W = (blockIdx.z == 0) ? W0 : (blockIdx.z == 1) ? W1 : W2;
  _Float16* o = WT + (size_t)blockIdx.z * D_DIM * D_DIM;
  __shared__ _Float16 tile[64][68];
  int k0 = blockIdx.x * 64, n0 = blockIdx.y * 64;
#pragma unroll
  for (int i = 0; i < 16; ++i) {
    int idx = threadIdx.x + i * 256;
    int r = idx >> 6, c = idx & 63;
    tile[r][c] = (_Float16)W[(size_t)(k0 + r) * D_DIM + n0 + c];
  }
  __syncthreads();
#pragma unroll
  for (int i = 0; i < 16; ++i) {
    int idx = threadIdx.x + i * 256;
    int r = idx >> 6, c = idx & 63;
    o[(size_t)(n0 + r) * D_DIM + k0 + c] = tile[c][r];
  }
}

// ============ 8-wave pipelined GEMM core: BM=BN=256, BK=32, 2 LDS slots ============
// 64 KB LDS -> 2 blocks/CU (4 waves/SIMD): cross-block overlap hides barrier/
// latency serialization (round-10 diagnosis: 1 block/CU left phases ~6x the
// LDS+MFMA floor). Depth-1 prefetch, counted vmcnt(4) steady / (0) tail; stage
// kt ages one full phase before the wait. B1 guarantees the overwritten slot's
// readers are done (in-order MFMA issue consumes reads before B1 is reached).
// 64B-row swizzle u' = u^((row>>1)&3): 2 lanes/bank = free (round 9: conflicts 0).
template <bool SWAP>
__device__ __forceinline__ void core256(const _Float16* __restrict__ Ag,
                                        const _Float16* __restrict__ Bg,
                                        int lda, int ldb, int k0, int nt,
                                        char* lds, float4_t (&acc)[8][4]) {
  const int tid = threadIdx.x;
  const int w = tid >> 6, l = tid & 63;
  const int wr = w >> 2, wc = w & 3;
  const int l15 = l & 15, l4 = l >> 4;

  int aSrc[2], bSrc[2], sDst[2];
#pragma unroll
  for (int i = 0; i < 2; ++i) {
    int L = i * 512 + tid;
    int row = L >> 2, u = L & 3;
    int usw = u ^ ((row >> 1) & 3);
    aSrc[i] = row * lda + usw * 8;
    bSrc[i] = row * ldb + usw * 8;
    sDst[i] = (i * 512 + (tid & ~63)) * 16;
  }

#define STG(kt)                                                               \
  do {                                                                        \
    char* slot = lds + ((kt) & 1) * 32768;                                    \
    const _Float16* Asrc = Ag + (size_t)(k0 + (kt)) * 32;                     \
    const _Float16* Bsrc = Bg + (size_t)(k0 + (kt)) * 32;                     \
    _Pragma("unroll") for (int i = 0; i < 2; ++i)                             \
        GLOAD_LDS16(Asrc + aSrc[i], slot + sDst[i]);                          \
    _Pragma("unroll") for (int i = 0; i < 2; ++i)                             \
        GLOAD_LDS16(Bsrc + bSrc[i], slot + 16384 + sDst[i]);                  \
  } while (0)

  if (nt > 0) STG(0);  // prologue: 1 stage in flight

#pragma unroll 1
  for (int kt = 0; kt < nt; ++kt) {
    __builtin_amdgcn_s_barrier();  // B1: all waves done reading slot (kt+1)&1
    if (kt + 1 < nt) STG(kt + 1);
    __builtin_amdgcn_sched_barrier(0);
    if (kt + 1 < nt)
      asm volatile("s_waitcnt vmcnt(4)" ::: "memory");  // stage kt landed
    else
      asm volatile("s_waitcnt vmcnt(0)" ::: "memory");
    __builtin_amdgcn_sched_barrier(0);
    __builtin_amdgcn_s_barrier();  // B2: every wave's stage(kt) is in LDS
    __builtin_amdgcn_sched_barrier(0);

    const char* As = lds + (kt & 1) * 32768;
    const char* Bs = As + 16384;
    half8_t bf[4];
#pragma unroll
    for (int ni = 0; ni < 4; ++ni) {
      int brow = wc * 64 + ni * 16 + l15;
      bf[ni] = *(const half8_t*)(Bs + brow * 64 + ((l4 ^ ((brow >> 1) & 3)) * 16));
    }
    __builtin_amdgcn_s_setprio(1);
#pragma unroll
    for (int mq = 0; mq < 2; ++mq) {
      half8_t af[4];
#pragma unroll
      for (int mi = 0; mi < 4; ++mi) {
        int arow = wr * 128 + (mq * 4 + mi) * 16 + l15;
        af[mi] = *(const half8_t*)(As + arow * 64 + ((l4 ^ ((arow >> 1) & 3)) * 16));
      }
#pragma unroll
      for (int mi = 0; mi < 4; ++mi)
#pragma unroll
        for (int ni = 0; ni < 4; ++ni) {
          if (SWAP)
            acc[mq * 4 + mi][ni] = mfma16(bf[ni], af[mi], acc[mq * 4 + mi][ni]);
          else
            acc[mq * 4 + mi][ni] = mfma16(af[mi], bf[ni], acc[mq * 4 + mi][ni]);
        }
    }
    __builtin_amdgcn_s_setprio(0);
  }
#undef STG
}

// ---------------- proj: q,k normal; v written directly transposed ----------------
__global__ __launch_bounds__(512, 4) void proj8_kernel(const _Float16* __restrict__ xh,
                                                       const _Float16* __restrict__ WT,
                                                       _Float16* __restrict__ qkv,
                                                       _Float16* __restrict__ vt) {
  __shared__ __align__(16) char lds[65536];
  const int bid = blockIdx.x;
  const int wid = (bid & 7) * 72 + (bid >> 3);
  const int rg2 = wid / 18;
  const int rem = wid % 18;
  const int z = rem / 6;
  const int cb = (rem % 6) >> 1;
  const int rbg = rg2 * 2 + (rem & 1);

  const _Float16* Ag = xh + (size_t)rbg * 256 * D_DIM;
  const _Float16* Bg = WT + (size_t)z * D_DIM * D_DIM + (size_t)cb * 256 * D_DIM;
  float4_t acc[8][4];
#pragma unroll
  for (int a = 0; a < 8; ++a)
#pragma unroll
    for (int b = 0; b < 4; ++b) acc[a][b] = (float4_t){0.f, 0.f, 0.f, 0.f};

  const int tid = threadIdx.x;
  const int w = tid >> 6, l = tid & 63;
  const int wr = w >> 2, wc = w & 3;
  const int l15 = l & 15, l4 = l >> 4;

  if (z < 2) {
    core256<false>(Ag, Bg, D_DIM, D_DIM, 0, 24, lds, acc);
    _Float16* C = qkv + (size_t)z * M_DIM * D_DIM;
#pragma unroll
    for (int mi = 0; mi < 8; ++mi)
#pragma unroll
      for (int ni = 0; ni < 4; ++ni) {
        int col = cb * 256 + wc * 64 + ni * 16 + l15;
#pragma unroll
        for (int j = 0; j < 4; ++j) {
          int row = rbg * 256 + wr * 128 + mi * 16 + l4 * 4 + j;
          C[(size_t)row * D_DIM + col] = (_Float16)acc[mi][ni][j];
        }
      }
  } else {
    core256<true>(Ag, Bg, D_DIM, D_DIM, 0, 24, lds, acc);
#pragma unroll
    for (int mi = 0; mi < 8; ++mi) {
      int scol = rbg * 256 + wr * 128 + mi * 16 + l15;
      int bb = scol >> 12;
      int sl = scol & 4095;
      _Float16* vtb = vt + (size_t)bb * SD;
#pragma unroll
      for (int ni = 0; ni < 4; ++ni) {
#pragma unroll
        for (int j = 0; j < 4; ++j) {
          int drow = cb * 256 + wc * 64 + ni * 16 + l4 * 4 + j;
          vtb[(size_t)drow * S_DIM + sl] = (_Float16)acc[mi][ni][j];
        }
      }
    }
  }
}

// ---------------- gemm1: P = exp(scale*QK^T - 4) causal ----------------
__global__ __launch_bounds__(512, 4) void gemm1_8_kernel(const _Float16* __restrict__ Q,
                                                         const _Float16* __restrict__ K,
                                                         _Float16* __restrict__ P,
                                                         float* __restrict__ rp) {
  __shared__ __align__(16) char lds[65536];
  const float SCALE = 0.036084391824351615f;  // 1/sqrt(768)
  const int bid = blockIdx.x;
  const int wid = (bid & 7) * 68 + (bid >> 3);
  const int z = wid / 136;
  const int t = wid % 136;
  int g, base;
  if (t < 10) { g = 0; base = 0; }
  else if (t < 36) { g = 1; base = 10; }
  else if (t < 78) { g = 2; base = 36; }
  else { g = 3; base = 78; }
  int r = t - base;
  int rbg, cb;
  if (r < 16 * g) {
    int cbg = r >> 4, wi = r & 15;
    rbg = 4 * g + (wi >> 2);
    cb = 4 * cbg + (wi & 3);
  } else {
    int r2 = r - 16 * g;
    const int ri[10] = {0, 1, 1, 2, 2, 2, 3, 3, 3, 3};
    const int rj[10] = {0, 0, 1, 0, 1, 2, 0, 1, 2, 3};
    rbg = 4 * g + ri[r2];
    cb = 4 * g + rj[r2];
  }

  const _Float16* Ag = Q + (size_t)z * SD + (size_t)rbg * 256 * D_DIM;
  const _Float16* Bg = K + (size_t)z * SD + (size_t)cb * 256 * D_DIM;
  float4_t acc[8][4];
#pragma unroll
  for (int a = 0; a < 8; ++a)
#pragma unroll
    for (int b = 0; b < 4; ++b) acc[a][b] = (float4_t){0.f, 0.f, 0.f, 0.f};
  core256<false>(Ag, Bg, D_DIM, D_DIM, 0, 24, lds, acc);

  const int tid = threadIdx.x;
  const int w = tid >> 6, l = tid & 63;
  const int wr = w >> 2, wc = w & 3;
  const int l15 = l & 15, l4 = l >> 4;
  _Float16* Pz = P + (size_t)z * S_DIM * S_DIM;
  float* rpz = rp + (size_t)z * S_DIM * 64;
#pragma unroll
  for (int mi = 0; mi < 8; ++mi) {
#pragma unroll
    for (int j = 0; j < 4; ++j) {
      int row = rbg * 256 + wr * 128 + mi * 16 + l4 * 4 + j;
      float rs = 0.f;
#pragma unroll
      for (int ni = 0; ni < 4; ++ni) {
        int col = cb * 256 + wc * 64 + ni * 16 + l15;
        float v = (col <= row) ? __expf(acc[mi][ni][j] * SCALE - 4.0f) : 0.f;
        _Float16 ph = (_Float16)v;
        Pz[(size_t)row * S_DIM + col] = ph;
        rs += (float)ph;
      }
#pragma unroll
      for (int d = 1; d < 16; d <<= 1) rs += __shfl_xor(rs, d);
      if (l15 == 0) rpz[(size_t)row * 64 + cb * 4 + wc] = rs;
    }
  }
}

// ---------------- rsum combine (deterministic) ----------------
__global__ __launch_bounds__(256) void rsum_combine_kernel(const float* __restrict__ rp,
                                                           float* __restrict__ rsum) {
  int idx = blockIdx.x * 256 + threadIdx.x;  // z*4096 + row
  int row = idx & 4095;
  int np = ((row >> 8) + 1) * 4;
  const float* p = rp + (size_t)idx * 64;
  float s = 0.f;
  for (int i = 0; i < np; ++i) s += p[i];
  rsum[idx] = s;
}

// ---------------- gemm2: out = (P @ VT^T)/rsum — uniform 64-step units ------
// 17 units per (z,by) pair exactly into 64 K-steps (1-2 jobs per block).
// Grid 208 (=8x26 XCD-bijective, wids>=204 idle); wid = z*51 + u*3 + by.
#define PART_STRIDE ((size_t)4 * 2048 * 768)
__global__ __launch_bounds__(512, 4) void gemm2_8_kernel(const _Float16* __restrict__ P,
                                                         const _Float16* __restrict__ VT,
                                                         float* __restrict__ outp,
                                                         _Float16* __restrict__ part,
                                                         const float* __restrict__ rsum) {
  __shared__ __align__(16) char lds[65536];
  const int bid = blockIdx.x;
  const int wid = (bid & 7) * 26 + (bid >> 3);
  if (wid >= 204) return;
  const int z = wid / 51;
  const int rem = wid % 51;
  const int u = rem / 3;
  const int by = rem % 3;
  int r1, c1, r2 = -1, c2 = 0;
  if (u < 9)        { r1 = 15 - u; c1 = 0; }
  else if (u == 9)  { r1 = 15;     c1 = 1; }
  else if (u < 13)  { r1 = 16 - u; c1 = 0; r2 = u - 10; c2 = 0; }
  else if (u == 13) { r1 = 3;      c1 = 0; r2 = 11;     c2 = 1; }
  else              { r1 = 28 - u; c1 = 1; r2 = u - 6;  c2 = 1; }

  const int tid = threadIdx.x;
  const int w = tid >> 6, l = tid & 63;
  const int wr = w >> 2, wc = w & 3;
  const int l15 = l & 15, l4 = l >> 4;
  const _Float16* Bg = VT + (size_t)z * SD + (size_t)by * 256 * S_DIM;

#pragma unroll 1
  for (int jj = 0; jj < 2; ++jj) {
    const int rbg = jj ? r2 : r1;
    if (rbg < 0) break;
    const int chk = jj ? c2 : c1;
    const int tot = 8 * (rbg + 1);
    const int k0 = chk * 64;
    const int nt = chk ? (tot - 64) : (tot < 64 ? tot : 64);
    const bool split = (tot > 64);
    if (jj) __syncthreads();  // job1 LDS readers done before job2 restages

    const _Float16* Ag = P + (size_t)z * S_DIM * S_DIM + (size_t)rbg * 256 * S_DIM;
    float4_t acc[8][4];
#pragma unroll
    for (int a = 0; a < 8; ++a)
#pragma unroll
      for (int b = 0; b < 4; ++b) acc[a][b] = (float4_t){0.f, 0.f, 0.f, 0.f};
    core256<false>(Ag, Bg, S_DIM, S_DIM, k0, nt, lds, acc);

#pragma unroll
    for (int mi = 0; mi < 8; ++mi) {
#pragma unroll
      for (int j = 0; j < 4; ++j) {
        int row = rbg * 256 + wr * 128 + mi * 16 + l4 * 4 + j;  // batch-local row
        if (!split) {
          float rinv = 1.0f / rsum[(size_t)z * S_DIM + row];
#pragma unroll
          for (int ni = 0; ni < 4; ++ni) {
            int col = by * 256 + wc * 64 + ni * 16 + l15;
            outp[(size_t)z * SD + (size_t)row * D_DIM + col] = acc[mi][ni][j] * rinv;
          }
        } else {
          int lr = row - 2048;
#pragma unroll
          for (int ni = 0; ni < 4; ++ni) {
            int col = by * 256 + wc * 64 + ni * 16 + l15;
            part[(size_t)chk * PART_STRIDE + ((size_t)z * 2048 + lr) * D_DIM + col] =
                (_Float16)acc[mi][ni][j];
          }
        }
      }
    }
  }
}

// ---------------- combine split-row partials: out = (p0+p1)*rinv ----------------
__global__ __launch_bounds__(256) void g2_combine_kernel(const _Float16* __restrict__ part,
                                                         const float* __restrict__ rsum,
                                                         float* __restrict__ outp) {
  int idx = blockIdx.x * 256 + threadIdx.x;  // f16x8 group over [4][2048][768]
  int z = idx / 196608;
  int rem = idx - z * 196608;
  int lr = rem / 96, c8 = rem - lr * 96;
  size_t off = ((size_t)z * 2048 + lr) * D_DIM + c8 * 8;
  half8_t p0 = *(const half8_t*)(part + off);
  half8_t p1 = *(const half8_t*)(part + PART_STRIDE + off);
  int row = 2048 + lr;
  float rinv = 1.0f / rsum[(size_t)z * S_DIM + row];
  float* o = outp + (size_t)z * SD + (size_t)row * D_DIM + c8 * 8;
#pragma unroll
  for (int e = 0; e < 8; ++e) o[e] = ((float)p0[e] + (float)p1[e]) * rinv;
}

extern "C" void kernel_launch(void* const* d_in, const int* in_sizes, int n_in,
                              void* d_out, int out_size, void* d_ws, size_t ws_size,
                              hipStream_t stream) {
  const float* x = (const float*)d_in[0];
  const float* Wq = (const float*)d_in[1];
  const float* Wk = (const float*)d_in[2];
  const float* Wv = (const float*)d_in[3];
  float* out = (float*)d_out;
  char* ws = (char*)d_ws;

  const size_t XH_B = (size_t)M_DIM * D_DIM * 2;      // 25,165,824
  const size_t QKV_B = 3 * XH_B;                      // 75,497,472
  const size_t VT_B = XH_B;                           // 25,165,824
  const size_t WT_B = (size_t)3 * D_DIM * D_DIM * 2;  // 3,538,944
  const size_t BASE_END = XH_B + QKV_B + VT_B + WT_B; // 129,368,064

  _Float16* xh = (_Float16*)ws;
  _Float16* qkv = (_Float16*)(ws + XH_B);
  _Float16* Q = qkv;
  _Float16* K = qkv + (size_t)M_DIM * D_DIM;
  _Float16* vt = (_Float16*)(ws + XH_B + QKV_B);
  _Float16* wt = (_Float16*)(ws + XH_B + QKV_B + VT_B);

  // tier-A layout (rounds 4-10 prove ws_size >= 267,845,632)
  float* rp = (float*)(ws + BASE_END);                        // 4 MB
  float* rsum = (float*)(ws + BASE_END + (size_t)4194304);    // 64 KB
  _Float16* P = (_Float16*)(ws + BASE_END + (size_t)4259840); // 134 MB
  _Float16* part = xh;  // overlay: xh dead after proj

  cvt_x_kernel<<<dim3(12288), dim3(256), 0, stream>>>(x, xh, M_DIM * D_DIM);
  transpose_w_kernel<<<dim3(12, 12, 3), dim3(256), 0, stream>>>(Wq, Wk, Wv, wt);
  proj8_kernel<<<dim3(576), dim3(512), 0, stream>>>(xh, wt, qkv, vt);
  gemm1_8_kernel<<<dim3(544), dim3(512), 0, stream>>>(Q, K, P, rp);
  rsum_combine_kernel<<<dim3(64), dim3(256), 0, stream>>>(rp, rsum);
  gemm2_8_kernel<<<dim3(208), dim3(512), 0, stream>>>(P, vt, out, part, rsum);
  g2_combine_kernel<<<dim3(3072), dim3(256), 0, stream>>>(part, rsum, out);
}

// Round 12
// 296.100 us; speedup vs baseline: 3.9743x; 3.9743x over previous
//
#include <hip/hip_runtime.h>
#include <hip/hip_bf16.h>

typedef __attribute__((ext_vector_type(8))) _Float16 half8_t;
typedef __attribute__((ext_vector_type(4))) _Float16 half4_t;
typedef __attribute__((ext_vector_type(4))) float float4_t;

#define D_DIM 768
#define S_DIM 4096
#define B_DIM 4
#define M_DIM (B_DIM * S_DIM)  // 16384
#define SD ((size_t)S_DIM * D_DIM)

#define GLOAD_LDS16(g, s)                                      \
  __builtin_amdgcn_global_load_lds(                            \
      (const __attribute__((address_space(1))) void*)(g),      \
      (__attribute__((address_space(3))) void*)(s), 16, 0, 0)

__device__ __forceinline__ float4_t mfma16(half8_t a, half8_t b, float4_t c) {
  return __builtin_amdgcn_mfma_f32_16x16x32_f16(a, b, c, 0, 0, 0);
}

// ---------------- x -> fp16 (vectorized) ----------------
__global__ __launch_bounds__(256) void cvt_x_kernel(const float* __restrict__ in,
                                                    _Float16* __restrict__ out, int n) {
  int i = (blockIdx.x * 256 + threadIdx.x) * 4;
  if (i < n) {
    float4 v = *(const float4*)(in + i);
    half4_t o;
    o.x = (_Float16)v.x; o.y = (_Float16)v.y; o.z = (_Float16)v.z; o.w = (_Float16)v.w;
    *(half4_t*)(out + i) = o;
  }
}

// ---------------- W (fp32 [k][n]) -> WT (fp16 [n][k]) ----------------
__global__ __launch_bounds__(256) void transpose_w_kernel(const float* __restrict__ W0,
                                                          const float* __restrict__ W1,
                                                          const float* __restrict__ W2,
                                                          _Float16* __restrict__ WT) {
  const float* W = (blockIdx.z == 0) ? W0 : (blockIdx.z == 1) ? W1 : W2;
  _Float16* o = WT + (size_t)blockIdx.z * D_DIM * D_DIM;
  __shared__ _Float16 tile[64][68];
  int k0 = blockIdx.x * 64, n0 = blockIdx.y * 64;
#pragma unroll
  for (int i = 0; i < 16; ++i) {
    int idx = threadIdx.x + i * 256;
    int r = idx >> 6, c = idx & 63;
    tile[r][c] = (_Float16)W[(size_t)(k0 + r) * D_DIM + n0 + c];
  }
  __syncthreads();
#pragma unroll
  for (int i = 0; i < 16; ++i) {
    int idx = threadIdx.x + i * 256;
    int r = idx >> 6, c = idx & 63;
    o[(size_t)(n0 + r) * D_DIM + k0 + c] = tile[c][r];
  }
}

// ============ 8-wave pipelined GEMM core: BM=BN=256, BK=32, 4 LDS slots ============
// Round-10 schedule (B1; STG(kt+3); counted vmcnt; B2; reads+MFMA) PLUS cross-phase
// fragment prefetch: steady vmcnt(8) guarantees stages kt AND kt+1 landed at B2, so
// each phase issues next-phase bf/af0 reads into a ping-pong register set; those
// 12 ds_reads stream under this phase's 32 MFMAs + barrier window (counted lgkmcnt
// lets them cross), and MFMAs start on pre-loaded registers. Loop 2x-unrolled so
// all register-set indices are static (no scratch). nt is always even here.
// 64B-row swizzle u' = u^((row>>1)&3): 2 lanes/bank = free (round 9: conflicts 0).
template <bool SWAP>
__device__ __forceinline__ void core256(const _Float16* __restrict__ Ag,
                                        const _Float16* __restrict__ Bg,
                                        int lda, int ldb, int k0, int nt,
                                        char* lds, float4_t (&acc)[8][4]) {
  const int tid = threadIdx.x;
  const int w = tid >> 6, l = tid & 63;
  const int wr = w >> 2, wc = w & 3;
  const int l15 = l & 15, l4 = l >> 4;

  int aSrc[2], bSrc[2], sDst[2];
#pragma unroll
  for (int i = 0; i < 2; ++i) {
    int L = i * 512 + tid;
    int row = L >> 2, u = L & 3;
    int usw = u ^ ((row >> 1) & 3);
    aSrc[i] = row * lda + usw * 8;
    bSrc[i] = row * ldb + usw * 8;
    sDst[i] = (i * 512 + (tid & ~63)) * 16;
  }

  // fixed per-thread LDS read offsets (within a 32 KB slot)
  int bOff[4], a0Off[4], a1Off[4];
#pragma unroll
  for (int ni = 0; ni < 4; ++ni) {
    int brow = wc * 64 + ni * 16 + l15;
    bOff[ni] = 16384 + brow * 64 + ((l4 ^ ((brow >> 1) & 3)) * 16);
  }
#pragma unroll
  for (int mi = 0; mi < 4; ++mi) {
    int r0 = wr * 128 + mi * 16 + l15;
    a0Off[mi] = r0 * 64 + ((l4 ^ ((r0 >> 1) & 3)) * 16);
    int r1 = wr * 128 + (4 + mi) * 16 + l15;
    a1Off[mi] = r1 * 64 + ((l4 ^ ((r1 >> 1) & 3)) * 16);
  }

#define STG(kt)                                                               \
  do {                                                                        \
    char* slot = lds + ((kt) & 3) * 32768;                                    \
    const _Float16* Asrc = Ag + (size_t)(k0 + (kt)) * 32;                     \
    const _Float16* Bsrc = Bg + (size_t)(k0 + (kt)) * 32;                     \
    _Pragma("unroll") for (int i = 0; i < 2; ++i)                             \
        GLOAD_LDS16(Asrc + aSrc[i], slot + sDst[i]);                          \
    _Pragma("unroll") for (int i = 0; i < 2; ++i)                             \
        GLOAD_LDS16(Bsrc + bSrc[i], slot + 16384 + sDst[i]);                  \
  } while (0)

  // prologue: up to 3 stages in flight; land stages 0,1; preload frag set A
  STG(0);
  if (nt > 1) STG(1);
  if (nt > 2) STG(2);
  if (nt > 2)
    asm volatile("s_waitcnt vmcnt(4)" ::: "memory");
  else
    asm volatile("s_waitcnt vmcnt(0)" ::: "memory");
  __builtin_amdgcn_s_barrier();

  half8_t bfA[4], a0A[4], bfB[4], a0B[4];
#pragma unroll
  for (int i = 0; i < 4; ++i) bfA[i] = *(const half8_t*)(lds + bOff[i]);
#pragma unroll
  for (int i = 0; i < 4; ++i) a0A[i] = *(const half8_t*)(lds + a0Off[i]);

  auto phase = [&](int kt, half8_t (&bfC)[4], half8_t (&a0C)[4],
                   half8_t (&bfN)[4], half8_t (&a0N)[4]) {
    __builtin_amdgcn_s_barrier();  // B1: all waves done reading slot (kt+3)&3
    if (kt + 3 < nt) STG(kt + 3);
    __builtin_amdgcn_sched_barrier(0);
    if (kt + 3 < nt)
      asm volatile("s_waitcnt vmcnt(8)" ::: "memory");   // kt, kt+1 landed
    else if (kt + 2 < nt)
      asm volatile("s_waitcnt vmcnt(4)" ::: "memory");   // kt, kt+1 landed
    else
      asm volatile("s_waitcnt vmcnt(0)" ::: "memory");
    __builtin_amdgcn_sched_barrier(0);
    __builtin_amdgcn_s_barrier();  // B2: all waves' stages kt, kt+1 in LDS
    const char* Sc = lds + (kt & 3) * 32768;
    half8_t a1[4];
#pragma unroll
    for (int i = 0; i < 4; ++i) a1[i] = *(const half8_t*)(Sc + a1Off[i]);
    if (kt + 1 < nt) {
      const char* Sn = lds + ((kt + 1) & 3) * 32768;
#pragma unroll
      for (int i = 0; i < 4; ++i) bfN[i] = *(const half8_t*)(Sn + bOff[i]);
#pragma unroll
      for (int i = 0; i < 4; ++i) a0N[i] = *(const half8_t*)(Sn + a0Off[i]);
    }
    __builtin_amdgcn_s_setprio(1);
#pragma unroll
    for (int mi = 0; mi < 4; ++mi)
#pragma unroll
      for (int ni = 0; ni < 4; ++ni) {
        if (SWAP)
          acc[mi][ni] = mfma16(bfC[ni], a0C[mi], acc[mi][ni]);
        else
          acc[mi][ni] = mfma16(a0C[mi], bfC[ni], acc[mi][ni]);
      }
#pragma unroll
    for (int mi = 0; mi < 4; ++mi)
#pragma unroll
      for (int ni = 0; ni < 4; ++ni) {
        if (SWAP)
          acc[4 + mi][ni] = mfma16(bfC[ni], a1[mi], acc[4 + mi][ni]);
        else
          acc[4 + mi][ni] = mfma16(a1[mi], bfC[ni], acc[4 + mi][ni]);
      }
    __builtin_amdgcn_s_setprio(0);
  };

#pragma unroll 1
  for (int kt = 0; kt < nt; kt += 2) {
    phase(kt, bfA, a0A, bfB, a0B);
    phase(kt + 1, bfB, a0B, bfA, a0A);
  }
#undef STG
}

// ---------------- proj: q,k normal; v written directly transposed ----------------
__global__ __launch_bounds__(512, 2) void proj8_kernel(const _Float16* __restrict__ xh,
                                                       const _Float16* __restrict__ WT,
                                                       _Float16* __restrict__ qkv,
                                                       _Float16* __restrict__ vt) {
  __shared__ __align__(16) char lds[131072];
  const int bid = blockIdx.x;
  const int wid = (bid & 7) * 72 + (bid >> 3);
  const int rg2 = wid / 18;
  const int rem = wid % 18;
  const int z = rem / 6;
  const int cb = (rem % 6) >> 1;
  const int rbg = rg2 * 2 + (rem & 1);

  const _Float16* Ag = xh + (size_t)rbg * 256 * D_DIM;
  const _Float16* Bg = WT + (size_t)z * D_DIM * D_DIM + (size_t)cb * 256 * D_DIM;
  float4_t acc[8][4];
#pragma unroll
  for (int a = 0; a < 8; ++a)
#pragma unroll
    for (int b = 0; b < 4; ++b) acc[a][b] = (float4_t){0.f, 0.f, 0.f, 0.f};

  const int tid = threadIdx.x;
  const int w = tid >> 6, l = tid & 63;
  const int wr = w >> 2, wc = w & 3;
  const int l15 = l & 15, l4 = l >> 4;

  if (z < 2) {
    core256<false>(Ag, Bg, D_DIM, D_DIM, 0, 24, lds, acc);
    _Float16* C = qkv + (size_t)z * M_DIM * D_DIM;
#pragma unroll
    for (int mi = 0; mi < 8; ++mi)
#pragma unroll
      for (int ni = 0; ni < 4; ++ni) {
        int col = cb * 256 + wc * 64 + ni * 16 + l15;
#pragma unroll
        for (int j = 0; j < 4; ++j) {
          int row = rbg * 256 + wr * 128 + mi * 16 + l4 * 4 + j;
          C[(size_t)row * D_DIM + col] = (_Float16)acc[mi][ni][j];
        }
      }
  } else {
    core256<true>(Ag, Bg, D_DIM, D_DIM, 0, 24, lds, acc);
#pragma unroll
    for (int mi = 0; mi < 8; ++mi) {
      int scol = rbg * 256 + wr * 128 + mi * 16 + l15;
      int bb = scol >> 12;
      int sl = scol & 4095;
      _Float16* vtb = vt + (size_t)bb * SD;
#pragma unroll
      for (int ni = 0; ni < 4; ++ni) {
#pragma unroll
        for (int j = 0; j < 4; ++j) {
          int drow = cb * 256 + wc * 64 + ni * 16 + l4 * 4 + j;
          vtb[(size_t)drow * S_DIM + sl] = (_Float16)acc[mi][ni][j];
        }
      }
    }
  }
}

// ---------------- gemm1: P = exp(scale*QK^T - 4) causal ----------------
__global__ __launch_bounds__(512, 2) void gemm1_8_kernel(const _Float16* __restrict__ Q,
                                                         const _Float16* __restrict__ K,
                                                         _Float16* __restrict__ P,
                                                         float* __restrict__ rp) {
  __shared__ __align__(16) char lds[131072];
  const float SCALE = 0.036084391824351615f;  // 1/sqrt(768)
  const int bid = blockIdx.x;
  const int wid = (bid & 7) * 68 + (bid >> 3);
  const int z = wid / 136;
  const int t = wid % 136;
  int g, base;
  if (t < 10) { g = 0; base = 0; }
  else if (t < 36) { g = 1; base = 10; }
  else if (t < 78) { g = 2; base = 36; }
  else { g = 3; base = 78; }
  int r = t - base;
  int rbg, cb;
  if (r < 16 * g) {
    int cbg = r >> 4, wi = r & 15;
    rbg = 4 * g + (wi >> 2);
    cb = 4 * cbg + (wi & 3);
  } else {
    int r2 = r - 16 * g;
    const int ri[10] = {0, 1, 1, 2, 2, 2, 3, 3, 3, 3};
    const int rj[10] = {0, 0, 1, 0, 1, 2, 0, 1, 2, 3};
    rbg = 4 * g + ri[r2];
    cb = 4 * g + rj[r2];
  }

  const _Float16* Ag = Q + (size_t)z * SD + (size_t)rbg * 256 * D_DIM;
  const _Float16* Bg = K + (size_t)z * SD + (size_t)cb * 256 * D_DIM;
  float4_t acc[8][4];
#pragma unroll
  for (int a = 0; a < 8; ++a)
#pragma unroll
    for (int b = 0; b < 4; ++b) acc[a][b] = (float4_t){0.f, 0.f, 0.f, 0.f};
  core256<false>(Ag, Bg, D_DIM, D_DIM, 0, 24, lds, acc);

  const int tid = threadIdx.x;
  const int w = tid >> 6, l = tid & 63;
  const int wr = w >> 2, wc = w & 3;
  const int l15 = l & 15, l4 = l >> 4;
  _Float16* Pz = P + (size_t)z * S_DIM * S_DIM;
  float* rpz = rp + (size_t)z * S_DIM * 64;
#pragma unroll
  for (int mi = 0; mi < 8; ++mi) {
#pragma unroll
    for (int j = 0; j < 4; ++j) {
      int row = rbg * 256 + wr * 128 + mi * 16 + l4 * 4 + j;
      float rs = 0.f;
#pragma unroll
      for (int ni = 0; ni < 4; ++ni) {
        int col = cb * 256 + wc * 64 + ni * 16 + l15;
        float v = (col <= row) ? __expf(acc[mi][ni][j] * SCALE - 4.0f) : 0.f;
        _Float16 ph = (_Float16)v;
        Pz[(size_t)row * S_DIM + col] = ph;
        rs += (float)ph;
      }
#pragma unroll
      for (int d = 1; d < 16; d <<= 1) rs += __shfl_xor(rs, d);
      if (l15 == 0) rpz[(size_t)row * 64 + cb * 4 + wc] = rs;
    }
  }
}

// ---------------- rsum combine (deterministic) ----------------
__global__ __launch_bounds__(256) void rsum_combine_kernel(const float* __restrict__ rp,
                                                           float* __restrict__ rsum) {
  int idx = blockIdx.x * 256 + threadIdx.x;  // z*4096 + row
  int row = idx & 4095;
  int np = ((row >> 8) + 1) * 4;
  const float* p = rp + (size_t)idx * 64;
  float s = 0.f;
  for (int i = 0; i < np; ++i) s += p[i];
  rsum[idx] = s;
}

// ---------------- gemm2: out = (P @ VT^T)/rsum — uniform 64-step units ------
// 17 units per (z,by) pair exactly into 64 K-steps (1-2 jobs per block).
// Grid 208 (=8x26 XCD-bijective, wids>=204 idle); wid = z*51 + u*3 + by.
#define PART_STRIDE ((size_t)4 * 2048 * 768)
__global__ __launch_bounds__(512, 2) void gemm2_8_kernel(const _Float16* __restrict__ P,
                                                         const _Float16* __restrict__ VT,
                                                         float* __restrict__ outp,
                                                         _Float16* __restrict__ part,
                                                         const float* __restrict__ rsum) {
  __shared__ __align__(16) char lds[131072];
  const int bid = blockIdx.x;
  const int wid = (bid & 7) * 26 + (bid >> 3);
  if (wid >= 204) return;
  const int z = wid / 51;
  const int rem = wid % 51;
  const int u = rem / 3;
  const int by = rem % 3;
  int r1, c1, r2 = -1, c2 = 0;
  if (u < 9)        { r1 = 15 - u; c1 = 0; }
  else if (u == 9)  { r1 = 15;     c1 = 1; }
  else if (u < 13)  { r1 = 16 - u; c1 = 0; r2 = u - 10; c2 = 0; }
  else if (u == 13) { r1 = 3;      c1 = 0; r2 = 11;     c2 = 1; }
  else              { r1 = 28 - u; c1 = 1; r2 = u - 6;  c2 = 1; }

  const int tid = threadIdx.x;
  const int w = tid >> 6, l = tid & 63;
  const int wr = w >> 2, wc = w & 3;
  const int l15 = l & 15, l4 = l >> 4;
  const _Float16* Bg = VT + (size_t)z * SD + (size_t)by * 256 * S_DIM;

#pragma unroll 1
  for (int jj = 0; jj < 2; ++jj) {
    const int rbg = jj ? r2 : r1;
    if (rbg < 0) break;
    const int chk = jj ? c2 : c1;
    const int tot = 8 * (rbg + 1);
    const int k0 = chk * 64;
    const int nt = chk ? (tot - 64) : (tot < 64 ? tot : 64);
    const bool split = (tot > 64);
    if (jj) __syncthreads();  // job1 LDS readers done before job2 restages

    const _Float16* Ag = P + (size_t)z * S_DIM * S_DIM + (size_t)rbg * 256 * S_DIM;
    float4_t acc[8][4];
#pragma unroll
    for (int a = 0; a < 8; ++a)
#pragma unroll
      for (int b = 0; b < 4; ++b) acc[a][b] = (float4_t){0.f, 0.f, 0.f, 0.f};
    core256<false>(Ag, Bg, S_DIM, S_DIM, k0, nt, lds, acc);

#pragma unroll
    for (int mi = 0; mi < 8; ++mi) {
#pragma unroll
      for (int j = 0; j < 4; ++j) {
        int row = rbg * 256 + wr * 128 + mi * 16 + l4 * 4 + j;  // batch-local row
        if (!split) {
          float rinv = 1.0f / rsum[(size_t)z * S_DIM + row];
#pragma unroll
          for (int ni = 0; ni < 4; ++ni) {
            int col = by * 256 + wc * 64 + ni * 16 + l15;
            outp[(size_t)z * SD + (size_t)row * D_DIM + col] = acc[mi][ni][j] * rinv;
          }
        } else {
          int lr = row - 2048;
#pragma unroll
          for (int ni = 0; ni < 4; ++ni) {
            int col = by * 256 + wc * 64 + ni * 16 + l15;
            part[(size_t)chk * PART_STRIDE + ((size_t)z * 2048 + lr) * D_DIM + col] =
                (_Float16)acc[mi][ni][j];
          }
        }
      }
    }
  }
}

// ---------------- combine split-row partials: out = (p0+p1)*rinv ----------------
__global__ __launch_bounds__(256) void g2_combine_kernel(const _Float16* __restrict__ part,
                                                         const float* __restrict__ rsum,
                                                         float* __restrict__ outp) {
  int idx = blockIdx.x * 256 + threadIdx.x;  // f16x8 group over [4][2048][768]
  int z = idx / 196608;
  int rem = idx - z * 196608;
  int lr = rem / 96, c8 = rem - lr * 96;
  size_t off = ((size_t)z * 2048 + lr) * D_DIM + c8 * 8;
  half8_t p0 = *(const half8_t*)(part + off);
  half8_t p1 = *(const half8_t*)(part + PART_STRIDE + off);
  int row = 2048 + lr;
  float rinv = 1.0f / rsum[(size_t)z * S_DIM + row];
  float* o = outp + (size_t)z * SD + (size_t)row * D_DIM + c8 * 8;
#pragma unroll
  for (int e = 0; e < 8; ++e) o[e] = ((float)p0[e] + (float)p1[e]) * rinv;
}

extern "C" void kernel_launch(void* const* d_in, const int* in_sizes, int n_in,
                              void* d_out, int out_size, void* d_ws, size_t ws_size,
                              hipStream_t stream) {
  const float* x = (const float*)d_in[0];
  const float* Wq = (const float*)d_in[1];
  const float* Wk = (const float*)d_in[2];
  const float* Wv = (const float*)d_in[3];
  float* out = (float*)d_out;
  char* ws = (char*)d_ws;

  const size_t XH_B = (size_t)M_DIM * D_DIM * 2;      // 25,165,824
  const size_t QKV_B = 3 * XH_B;                      // 75,497,472
  const size_t VT_B = XH_B;                           // 25,165,824
  const size_t WT_B = (size_t)3 * D_DIM * D_DIM * 2;  // 3,538,944
  const size_t BASE_END = XH_B + QKV_B + VT_B + WT_B; // 129,368,064

  _Float16* xh = (_Float16*)ws;
  _Float16* qkv = (_Float16*)(ws + XH_B);
  _Float16* Q = qkv;
  _Float16* K = qkv + (size_t)M_DIM * D_DIM;
  _Float16* vt = (_Float16*)(ws + XH_B + QKV_B);
  _Float16* wt = (_Float16*)(ws + XH_B + QKV_B + VT_B);

  // tier-A layout (rounds 4-11 prove ws_size >= 267,845,632)
  float* rp = (float*)(ws + BASE_END);                        // 4 MB
  float* rsum = (float*)(ws + BASE_END + (size_t)4194304);    // 64 KB
  _Float16* P = (_Float16*)(ws + BASE_END + (size_t)4259840); // 134 MB
  _Float16* part = xh;  // overlay: xh dead after proj

  cvt_x_kernel<<<dim3(12288), dim3(256), 0, stream>>>(x, xh, M_DIM * D_DIM);
  transpose_w_kernel<<<dim3(12, 12, 3), dim3(256), 0, stream>>>(Wq, Wk, Wv, wt);
  proj8_kernel<<<dim3(576), dim3(512), 0, stream>>>(xh, wt, qkv, vt);
  gemm1_8_kernel<<<dim3(544), dim3(512), 0, stream>>>(Q, K, P, rp);
  rsum_combine_kernel<<<dim3(64), dim3(256), 0, stream>>>(rp, rsum);
  gemm2_8_kernel<<<dim3(208), dim3(512), 0, stream>>>(P, vt, out, part, rsum);
  g2_combine_kernel<<<dim3(3072), dim3(256), 0, stream>>>(part, rsum, out);
}